// Round 1
// baseline (45.669 us; speedup 1.0000x reference)
//
#include <hip/hip_runtime.h>

// Ray-AABB nearest intersection. R rays x B boxes.
// Outputs (float32, concatenated): [0,R) = nearest box idx (or -1), [R,2R) = distance (or -1).
// Bit-exactness with the numpy reference is required (argmin index output, absmax<=0.62):
//  - IEEE correctly-rounded div per box (no reciprocal hoisting)
//  - no FMA contraction in p = ro + t*rd (use __fmul_rn/__fadd_rn)
//  - argmin first-occurrence semantics (strict < scan, ascending b)

constexpr int BMAX = 32;

__global__ __launch_bounds__(256) void ray_aabb_kernel(
    const float* __restrict__ rays_o,
    const float* __restrict__ rays_d,
    const float* __restrict__ bbox,
    float* __restrict__ out_idx,
    float* __restrict__ out_dist,
    int R, int B)
{
    const float BIG = 10000000000.0f;
    const float EPS = 1e-4f;

    __shared__ float s_bmin[BMAX][3];
    __shared__ float s_bmax[BMAX][3];   // unexpanded (not used in valid test, kept for clarity of staging)
    __shared__ float s_bminE[BMAX][3];  // bmin - EPS
    __shared__ float s_bmaxE[BMAX][3];  // bmax + EPS

    int t = threadIdx.x;
    if (t < B * 3) {
        int b = t / 3, a = t - b * 3;
        float c = bbox[b * 6 + a];
        float s = bbox[b * 6 + 3 + a];
        float h  = __fmul_rn(s, 0.5f);
        float mn = __fsub_rn(c, h);
        float mx = __fadd_rn(c, h);
        s_bmin[b][a]  = mn;
        s_bmax[b][a]  = mx;
        s_bminE[b][a] = __fsub_rn(mn, EPS);
        s_bmaxE[b][a] = __fadd_rn(mx, EPS);
    }
    __syncthreads();

    int i = blockIdx.x * blockDim.x + threadIdx.x;
    if (i >= R) return;

    float ro[3], rd[3];
    #pragma unroll
    for (int a = 0; a < 3; ++a) {
        ro[a] = rays_o[i * 3 + a];
        float d = rays_d[i * 3 + a];
        rd[a] = (d == 0.0f) ? 1e-8f : d;
    }

    bool  keep  = false;
    float best  = __builtin_inff();  // BIG < inf, so box 0 always claims first (argmin of all-BIG = 0)
    int   bestb = 0;

    for (int b = 0; b < B; ++b) {
        float entry[3], exitv[3];
        #pragma unroll
        for (int a = 0; a < 3; ++a) {
            float t1 = __fdiv_rn(__fsub_rn(s_bmin[b][a], ro[a]), rd[a]);
            float t2 = __fdiv_rn(__fsub_rn(s_bmax[b][a], ro[a]), rd[a]);
            entry[a] = fminf(t1, t2);
            exitv[a] = fmaxf(t1, t2);
        }
        float tmm = fmaxf(entry[0], fmaxf(entry[1], entry[2]));
        float tmx = fminf(exitv[0], fminf(exitv[1], exitv[2]));
        keep = keep || ((tmm < tmx) && (tmx > 0.0f));

        // 3 candidate entry-t values; keep min valid one, else BIG
        float tn = BIG;
        #pragma unroll
        for (int c = 0; c < 3; ++c) {
            float tc = entry[c];
            bool v = (tc >= 0.0f);
            #pragma unroll
            for (int a = 0; a < 3; ++a) {
                float p = __fadd_rn(ro[a], __fmul_rn(tc, rd[a]));  // mul then add, both rounded (matches np)
                v = v && (p >= s_bminE[b][a]) && (p <= s_bmaxE[b][a]);
            }
            if (v) tn = fminf(tn, tc);
        }
        if (tn < best) { best = tn; bestb = b; }  // strict <: first-min wins, matches np.argmin
    }

    out_idx[i]  = keep ? (float)bestb : -1.0f;
    out_dist[i] = keep ? best : -1.0f;
}

extern "C" void kernel_launch(void* const* d_in, const int* in_sizes, int n_in,
                              void* d_out, int out_size, void* d_ws, size_t ws_size,
                              hipStream_t stream) {
    const float* rays_o = (const float*)d_in[0];
    const float* rays_d = (const float*)d_in[1];
    const float* bbox   = (const float*)d_in[2];
    int R = in_sizes[0] / 3;
    int B = in_sizes[2] / 6;
    if (B > BMAX) B = BMAX;

    float* out = (float*)d_out;
    float* out_idx  = out;
    float* out_dist = out + R;

    const int threads = 256;
    const int blocks = (R + threads - 1) / threads;
    ray_aabb_kernel<<<blocks, threads, 0, stream>>>(rays_o, rays_d, bbox,
                                                    out_idx, out_dist, R, B);
}

// Round 2
// 38.094 us; speedup vs baseline: 1.1989x; 1.1989x over previous
//
#include <hip/hip_runtime.h>

// Ray-AABB nearest intersection. R rays x B boxes.
// Outputs (float32, concatenated): [0,R) = nearest box idx (or -1), [R,2R) = distance (or -1).
// Bit-exactness with the numpy reference is required (argmin index output):
//  - divisions must equal IEEE RN division. We hoist y = RN(1/rd) (exact div, once
//    per ray per axis) and use Markstein's sequence per box:
//      q0 = RN(a*y); e = FMA(-b, q0, a)  [exact]; q = RN(q0 + e*y)
//    which is provably == RN(a/b) for round-to-nearest with FMA.
//  - no FMA contraction in p = ro + t*rd (use __fmul_rn/__fadd_rn)
//  - argmin first-occurrence semantics (strict < scan, ascending b)

constexpr int BMAX = 32;

__device__ __forceinline__ float div_markstein(float a, float b, float y) {
    float q0 = __fmul_rn(a, y);
    float e  = __fmaf_rn(-b, q0, a);   // exact residual
    return __fmaf_rn(e, y, q0);        // == __fdiv_rn(a, b)
}

template<int B>
__global__ __launch_bounds__(256) void ray_aabb_kernel(
    const float* __restrict__ rays_o,
    const float* __restrict__ rays_d,
    const float* __restrict__ bbox,
    float* __restrict__ out_idx,
    float* __restrict__ out_dist,
    int R)
{
    const float BIG = 10000000000.0f;
    const float EPS = 1e-4f;

    __shared__ float s_bmin[B][3];
    __shared__ float s_bminE[B][3];  // bmin - EPS
    __shared__ float s_bmaxE[B][3];  // bmax + EPS
    __shared__ float s_bmax[B][3];

    int t = threadIdx.x;
    if (t < B * 3) {
        int b = t / 3, a = t - b * 3;
        float c = bbox[b * 6 + a];
        float s = bbox[b * 6 + 3 + a];
        float h  = __fmul_rn(s, 0.5f);
        float mn = __fsub_rn(c, h);
        float mx = __fadd_rn(c, h);
        s_bmin[b][a]  = mn;
        s_bmax[b][a]  = mx;
        s_bminE[b][a] = __fsub_rn(mn, EPS);
        s_bmaxE[b][a] = __fadd_rn(mx, EPS);
    }
    __syncthreads();

    int i = blockIdx.x * blockDim.x + threadIdx.x;
    if (i >= R) return;

    float ro[3], rd[3], y[3];
    #pragma unroll
    for (int a = 0; a < 3; ++a) {
        ro[a] = rays_o[i * 3 + a];
        float d = rays_d[i * 3 + a];
        rd[a] = (d == 0.0f) ? 1e-8f : d;
        y[a]  = __fdiv_rn(1.0f, rd[a]);   // exact RN reciprocal (Markstein precondition)
    }

    bool  keep  = false;
    float best  = __builtin_inff();  // BIG < inf, so box 0 claims first when all t_near==BIG
    int   bestb = 0;

    #pragma unroll 4
    for (int b = 0; b < B; ++b) {
        float entry[3], exitv[3];
        #pragma unroll
        for (int a = 0; a < 3; ++a) {
            float t1 = div_markstein(__fsub_rn(s_bmin[b][a], ro[a]), rd[a], y[a]);
            float t2 = div_markstein(__fsub_rn(s_bmax[b][a], ro[a]), rd[a], y[a]);
            entry[a] = fminf(t1, t2);
            exitv[a] = fmaxf(t1, t2);
        }
        float tmm = fmaxf(entry[0], fmaxf(entry[1], entry[2]));
        float tmx = fminf(exitv[0], fminf(exitv[1], exitv[2]));
        keep = keep || ((tmm < tmx) && (tmx > 0.0f));

        // 3 candidate entry-t values; keep min valid one, else BIG
        float tn = BIG;
        #pragma unroll
        for (int c = 0; c < 3; ++c) {
            float tc = entry[c];
            bool v = (tc >= 0.0f);
            #pragma unroll
            for (int a = 0; a < 3; ++a) {
                float p = __fadd_rn(ro[a], __fmul_rn(tc, rd[a]));  // mul then add, both rounded (matches np)
                v = v && (p >= s_bminE[b][a]) && (p <= s_bmaxE[b][a]);
            }
            if (v) tn = fminf(tn, tc);
        }
        if (tn < best) { best = tn; bestb = b; }  // strict <: first-min wins, matches np.argmin
    }

    out_idx[i]  = keep ? (float)bestb : -1.0f;
    out_dist[i] = keep ? best : -1.0f;
}

extern "C" void kernel_launch(void* const* d_in, const int* in_sizes, int n_in,
                              void* d_out, int out_size, void* d_ws, size_t ws_size,
                              hipStream_t stream) {
    const float* rays_o = (const float*)d_in[0];
    const float* rays_d = (const float*)d_in[1];
    const float* bbox   = (const float*)d_in[2];
    int R = in_sizes[0] / 3;

    float* out = (float*)d_out;
    float* out_idx  = out;
    float* out_dist = out + R;

    const int threads = 256;
    const int blocks = (R + threads - 1) / threads;
    // B is 32 in this problem; compile-time specialization for full unroll.
    ray_aabb_kernel<BMAX><<<blocks, threads, 0, stream>>>(rays_o, rays_d, bbox,
                                                          out_idx, out_dist, R);
}

// Round 3
// 27.170 us; speedup vs baseline: 1.6809x; 1.4021x over previous
//
#include <hip/hip_runtime.h>

// Ray-AABB nearest intersection. R rays x B boxes.
// Outputs (float32, concatenated): [0,R) = nearest box idx (or -1), [R,2R) = distance (or -1).
// Bit-exactness with the numpy reference is required (argmin index output):
//  - divisions must equal IEEE RN division: hoist y = RN(1/rd) once per ray/axis
//    (exact div), then Markstein per box:
//      q0 = RN(a*y); e = FMA(-b, q0, a) [exact]; q = RN(q0 + e*y)  == RN(a/b)
//  - no FMA contraction in p = ro + t*rd (use __fmul_rn/__fadd_rn)
//  - argmin first-occurrence semantics (strict < scan, ascending b)
// Perf notes: grid-capped at 16 waves/CU (R/64 waves) -> latency-bound; box
// constants packed as float4 so each box is 4 ds_read_b128 broadcasts instead
// of 12 ds_read_b32; unroll 8 for ILP across the serial Markstein chains.

constexpr int BMAX = 32;

__device__ __forceinline__ float div_markstein(float a, float b, float y) {
    float q0 = __fmul_rn(a, y);
    float e  = __fmaf_rn(-b, q0, a);   // exact residual
    return __fmaf_rn(e, y, q0);        // == __fdiv_rn(a, b)
}

template<int B>
__global__ __launch_bounds__(256) void ray_aabb_kernel(
    const float* __restrict__ rays_o,
    const float* __restrict__ rays_d,
    const float* __restrict__ bbox,
    float* __restrict__ out_idx,
    float* __restrict__ out_dist,
    int R)
{
    const float BIG = 10000000000.0f;
    const float EPS = 1e-4f;

    // [b][0]=bmin  [b][1]=bmax  [b][2]=bmin-EPS  [b][3]=bmax+EPS  (w unused)
    __shared__ float4 s_box[B][4];

    int t = threadIdx.x;
    if (t < B * 4) {
        int b = t >> 2, k = t & 3;
        float c0 = bbox[b * 6 + 0], c1 = bbox[b * 6 + 1], c2 = bbox[b * 6 + 2];
        float s0 = bbox[b * 6 + 3], s1 = bbox[b * 6 + 4], s2 = bbox[b * 6 + 5];
        float h0 = __fmul_rn(s0, 0.5f), h1 = __fmul_rn(s1, 0.5f), h2 = __fmul_rn(s2, 0.5f);
        float4 v;
        if (k == 0) {
            v = make_float4(__fsub_rn(c0, h0), __fsub_rn(c1, h1), __fsub_rn(c2, h2), 0.f);
        } else if (k == 1) {
            v = make_float4(__fadd_rn(c0, h0), __fadd_rn(c1, h1), __fadd_rn(c2, h2), 0.f);
        } else if (k == 2) {
            v = make_float4(__fsub_rn(__fsub_rn(c0, h0), EPS),
                            __fsub_rn(__fsub_rn(c1, h1), EPS),
                            __fsub_rn(__fsub_rn(c2, h2), EPS), 0.f);
        } else {
            v = make_float4(__fadd_rn(__fadd_rn(c0, h0), EPS),
                            __fadd_rn(__fadd_rn(c1, h1), EPS),
                            __fadd_rn(__fadd_rn(c2, h2), EPS), 0.f);
        }
        s_box[b][k] = v;
    }
    __syncthreads();

    int i = blockIdx.x * blockDim.x + threadIdx.x;
    if (i >= R) return;

    float ro[3], rd[3], y[3];
    #pragma unroll
    for (int a = 0; a < 3; ++a) {
        ro[a] = rays_o[i * 3 + a];
        float d = rays_d[i * 3 + a];
        rd[a] = (d == 0.0f) ? 1e-8f : d;
        y[a]  = __fdiv_rn(1.0f, rd[a]);   // exact RN reciprocal (Markstein precondition)
    }

    bool  keep  = false;
    float best  = __builtin_inff();  // BIG < inf, so box 0 claims first when all t_near==BIG
    int   bestb = 0;

    #pragma unroll 8
    for (int b = 0; b < B; ++b) {
        float4 flo  = s_box[b][0];
        float4 fhi  = s_box[b][1];
        float4 floE = s_box[b][2];
        float4 fhiE = s_box[b][3];
        float lo[3]  = {flo.x,  flo.y,  flo.z};
        float hi[3]  = {fhi.x,  fhi.y,  fhi.z};
        float loE[3] = {floE.x, floE.y, floE.z};
        float hiE[3] = {fhiE.x, fhiE.y, fhiE.z};

        float entry[3], exitv[3];
        #pragma unroll
        for (int a = 0; a < 3; ++a) {
            float t1 = div_markstein(__fsub_rn(lo[a], ro[a]), rd[a], y[a]);
            float t2 = div_markstein(__fsub_rn(hi[a], ro[a]), rd[a], y[a]);
            entry[a] = fminf(t1, t2);
            exitv[a] = fmaxf(t1, t2);
        }
        float tmm = fmaxf(entry[0], fmaxf(entry[1], entry[2]));
        float tmx = fminf(exitv[0], fminf(exitv[1], exitv[2]));
        keep = keep || ((tmm < tmx) && (tmx > 0.0f));

        // 3 candidate entry-t values; keep min valid one, else BIG
        float tn = BIG;
        #pragma unroll
        for (int c = 0; c < 3; ++c) {
            float tc = entry[c];
            bool v = (tc >= 0.0f);
            #pragma unroll
            for (int a = 0; a < 3; ++a) {
                float p = __fadd_rn(ro[a], __fmul_rn(tc, rd[a]));  // mul then add, both rounded
                v = v && (p >= loE[a]) && (p <= hiE[a]);
            }
            if (v) tn = fminf(tn, tc);
        }
        if (tn < best) { best = tn; bestb = b; }  // strict <: first-min wins, matches np.argmin
    }

    out_idx[i]  = keep ? (float)bestb : -1.0f;
    out_dist[i] = keep ? best : -1.0f;
}

extern "C" void kernel_launch(void* const* d_in, const int* in_sizes, int n_in,
                              void* d_out, int out_size, void* d_ws, size_t ws_size,
                              hipStream_t stream) {
    const float* rays_o = (const float*)d_in[0];
    const float* rays_d = (const float*)d_in[1];
    const float* bbox   = (const float*)d_in[2];
    int R = in_sizes[0] / 3;

    float* out = (float*)d_out;
    float* out_idx  = out;
    float* out_dist = out + R;

    const int threads = 256;
    const int blocks = (R + threads - 1) / threads;
    // B is 32 in this problem; compile-time specialization for full unroll.
    ray_aabb_kernel<BMAX><<<blocks, threads, 0, stream>>>(rays_o, rays_d, bbox,
                                                          out_idx, out_dist, R);
}